// Round 1
// baseline (1851.577 us; speedup 1.0000x reference)
//
#include <hip/hip_runtime.h>

#define NU 100000
#define NI 200000
#define NE 1000000
#define NB 4096

// ---------------- degree + norm ----------------
__global__ __launch_bounds__(256) void deg_kernel(const int* __restrict__ src,
                                                  const int* __restrict__ dst,
                                                  float* __restrict__ deg_u,
                                                  float* __restrict__ deg_i) {
  int e = blockIdx.x * 256 + threadIdx.x;
  if (e < NE) {
    atomicAdd(&deg_u[src[e]], 1.0f);
    atomicAdd(&deg_i[dst[e]], 1.0f);
  }
}

__global__ __launch_bounds__(256) void norm_kernel(const int* __restrict__ src,
                                                   const int* __restrict__ dst,
                                                   const float* __restrict__ deg_u,
                                                   const float* __restrict__ deg_i,
                                                   float* __restrict__ normv) {
  int e = blockIdx.x * 256 + threadIdx.x;
  if (e < NE) {
    normv[e] = rsqrtf(deg_u[src[e]] * deg_i[dst[e]]);
  }
}

// ---------------- dense: a = h @ W1[l] + b1[l] for users then items ----------------
// one wave per row; lane j owns output column j; W1 column j lives in 64 VGPRs.
__global__ __launch_bounds__(256) void dense_kernel(const float* __restrict__ hu,
                                                    const float* __restrict__ hi,
                                                    const float* __restrict__ W1,
                                                    const float* __restrict__ b1,
                                                    float* __restrict__ a_u,
                                                    float* __restrict__ a_i) {
  __shared__ float rowbuf[4][64];
  const int lane = threadIdx.x & 63;
  const int w = threadIdx.x >> 6;
  float wcol[64];
#pragma unroll
  for (int k = 0; k < 64; ++k) wcol[k] = W1[k * 64 + lane];
  const float bv = b1[lane];
  const int nwaves = gridDim.x * 4;
  for (int r = blockIdx.x * 4 + w; r < NU + NI; r += nwaves) {
    const float* hrow = (r < NU) ? (hu + (size_t)r * 64) : (hi + (size_t)(r - NU) * 64);
    float* arow = (r < NU) ? (a_u + (size_t)r * 64) : (a_i + (size_t)(r - NU) * 64);
    float h = hrow[lane];
    rowbuf[w][lane] = h;
    float acc = bv;
#pragma unroll
    for (int k = 0; k < 16; ++k) {
      float4 p4 = *(const float4*)&rowbuf[w][k * 4];
      acc += p4.x * wcol[4 * k + 0];
      acc += p4.y * wcol[4 * k + 1];
      acc += p4.z * wcol[4 * k + 2];
      acc += p4.w * wcol[4 * k + 3];
    }
    arow[lane] = acc;
  }
}

// ---------------- edge kernel ----------------
// one wave per edge; lane j owns column j.
// p = hu[src]*hi[dst]; pw = p @ W2 + b2 (W2 col in regs, p broadcast via LDS)
// hi_new[dst] += norm*(a_u[src] + pw);  hu_new[src] += norm*(a_i[dst] + pw)
__global__ __launch_bounds__(256) void edge_kernel(const int* __restrict__ src,
                                                   const int* __restrict__ dst,
                                                   const float* __restrict__ normv,
                                                   const float* __restrict__ hu,
                                                   const float* __restrict__ hi,
                                                   const float* __restrict__ a_u,
                                                   const float* __restrict__ a_i,
                                                   const float* __restrict__ W2,
                                                   const float* __restrict__ b2,
                                                   float* __restrict__ hu_new,
                                                   float* __restrict__ hi_new) {
  __shared__ float ps[4][64];
  const int lane = threadIdx.x & 63;
  const int w = threadIdx.x >> 6;
  float wcol[64];
#pragma unroll
  for (int k = 0; k < 64; ++k) wcol[k] = W2[k * 64 + lane];
  const float bv = b2[lane];
  const int nwaves = gridDim.x * 4;
  for (int e = blockIdx.x * 4 + w; e < NE; e += nwaves) {
    const int s = src[e];
    const int d = dst[e];
    const float nrm = normv[e];
    const float huv = hu[(size_t)s * 64 + lane];
    const float hiv = hi[(size_t)d * 64 + lane];
    ps[w][lane] = huv * hiv;
    float acc = bv;
#pragma unroll
    for (int k = 0; k < 16; ++k) {
      float4 p4 = *(const float4*)&ps[w][k * 4];
      acc += p4.x * wcol[4 * k + 0];
      acc += p4.y * wcol[4 * k + 1];
      acc += p4.z * wcol[4 * k + 2];
      acc += p4.w * wcol[4 * k + 3];
    }
    const float au = a_u[(size_t)s * 64 + lane];
    const float ai = a_i[(size_t)d * 64 + lane];
    atomicAdd(&hi_new[(size_t)d * 64 + lane], nrm * (au + acc));
    atomicAdd(&hu_new[(size_t)s * 64 + lane], nrm * (ai + acc));
  }
}

// ---------------- leaky_relu + row L2 normalize (in place) ----------------
__global__ __launch_bounds__(256) void actnorm_kernel(float* __restrict__ h, int nrows) {
  const int lane = threadIdx.x & 63;
  const int w = threadIdx.x >> 6;
  const int nwaves = gridDim.x * 4;
  for (int r = blockIdx.x * 4 + w; r < nrows; r += nwaves) {
    float v = h[(size_t)r * 64 + lane];
    v = (v > 0.0f) ? v : 0.2f * v;
    float ss = v * v;
#pragma unroll
    for (int off = 32; off; off >>= 1) ss += __shfl_xor(ss, off);
    float n = sqrtf(ss);
    float inv = 1.0f / fmaxf(n, 1e-12f);
    h[(size_t)r * 64 + lane] = v * inv;
  }
}

// ---------------- gather one 64-col stage slice into the 3 outputs ----------------
__global__ __launch_bounds__(256) void gather_kernel(const float* __restrict__ hu,
                                                     const float* __restrict__ hi,
                                                     const int* __restrict__ users,
                                                     const int* __restrict__ pos,
                                                     const int* __restrict__ neg,
                                                     float* __restrict__ out,
                                                     int stage) {
  int t = blockIdx.x * 256 + threadIdx.x;
  if (t >= 3 * NB * 64) return;
  int j = t & 63;
  int b = (t >> 6) & (NB - 1);
  int which = t / (NB * 64);
  int row = (which == 0) ? users[b] : ((which == 1) ? pos[b] : neg[b]);
  const float* h = (which == 0) ? hu : hi;
  out[(size_t)which * NB * 256 + (size_t)b * 256 + (size_t)stage * 64 + j] =
      h[(size_t)row * 64 + j];
}

extern "C" void kernel_launch(void* const* d_in, const int* in_sizes, int n_in,
                              void* d_out, int out_size, void* d_ws, size_t ws_size,
                              hipStream_t stream) {
  (void)in_sizes; (void)n_in; (void)out_size; (void)ws_size;
  const float* user_feat = (const float*)d_in[0];
  const float* item_feat = (const float*)d_in[1];
  const float* W1 = (const float*)d_in[2];
  const float* b1 = (const float*)d_in[3];
  const float* W2 = (const float*)d_in[4];
  const float* b2 = (const float*)d_in[5];
  const int* edge_src = (const int*)d_in[6];
  const int* edge_dst = (const int*)d_in[7];
  const int* users = (const int*)d_in[8];
  const int* pos_items = (const int*)d_in[9];
  const int* neg_items = (const int*)d_in[10];
  float* out = (float*)d_out;

  char* p = (char*)d_ws;
  size_t ofs = 0;
  auto alloc = [&](size_t nf) -> float* {
    float* r = (float*)(p + ofs);
    ofs += ((nf * 4 + 1023) / 1024) * 1024;
    return r;
  };
  float* deg_u = alloc(NU);
  float* deg_i = alloc(NI);
  float* normv = alloc(NE);
  float* bufU0 = alloc((size_t)NU * 64);
  float* bufU1 = alloc((size_t)NU * 64);
  float* bufI0 = alloc((size_t)NI * 64);
  float* bufI1 = alloc((size_t)NI * 64);
  float* a_u = alloc((size_t)NU * 64);
  float* a_i = alloc((size_t)NI * 64);
  float* bufU[2] = {bufU0, bufU1};
  float* bufI[2] = {bufI0, bufI1};

  hipMemsetAsync(deg_u, 0, (size_t)NU * 4, stream);
  hipMemsetAsync(deg_i, 0, (size_t)NI * 4, stream);
  deg_kernel<<<(NE + 255) / 256, 256, 0, stream>>>(edge_src, edge_dst, deg_u, deg_i);
  norm_kernel<<<(NE + 255) / 256, 256, 0, stream>>>(edge_src, edge_dst, deg_u, deg_i, normv);

  gather_kernel<<<(3 * NB * 64 + 255) / 256, 256, 0, stream>>>(
      user_feat, item_feat, users, pos_items, neg_items, out, 0);

  const float* hu = user_feat;
  const float* hi = item_feat;
  for (int l = 0; l < 3; ++l) {
    float* hu_new = bufU[l & 1];
    float* hi_new = bufI[l & 1];
    dense_kernel<<<2048, 256, 0, stream>>>(hu, hi, W1 + l * 4096, b1 + l * 64, a_u, a_i);
    hipMemsetAsync(hu_new, 0, (size_t)NU * 64 * 4, stream);
    hipMemsetAsync(hi_new, 0, (size_t)NI * 64 * 4, stream);
    edge_kernel<<<4096, 256, 0, stream>>>(edge_src, edge_dst, normv, hu, hi, a_u, a_i,
                                          W2 + l * 4096, b2 + l * 64, hu_new, hi_new);
    actnorm_kernel<<<1024, 256, 0, stream>>>(hu_new, NU);
    actnorm_kernel<<<1024, 256, 0, stream>>>(hi_new, NI);
    gather_kernel<<<(3 * NB * 64 + 255) / 256, 256, 0, stream>>>(
        hu_new, hi_new, users, pos_items, neg_items, out, l + 1);
    hu = hu_new;
    hi = hi_new;
  }
}

// Round 2
// 1253.224 us; speedup vs baseline: 1.4775x; 1.4775x over previous
//
#include <hip/hip_runtime.h>

#define NU 100000
#define NI 200000
#define NE 1000000
#define NB 4096

// ================= setup: degree histogram =================
__global__ __launch_bounds__(256) void hist_kernel(const int* __restrict__ src,
                                                   const int* __restrict__ dst,
                                                   int* __restrict__ cnt_u,
                                                   int* __restrict__ cnt_i) {
  int e = blockIdx.x * 256 + threadIdx.x;
  if (e < NE) {
    atomicAdd(&cnt_u[src[e]], 1);
    atomicAdd(&cnt_i[dst[e]], 1);
  }
}

__global__ __launch_bounds__(256) void normv_kernel(const int* __restrict__ src,
                                                    const int* __restrict__ dst,
                                                    const int* __restrict__ cnt_u,
                                                    const int* __restrict__ cnt_i,
                                                    float* __restrict__ normv) {
  int e = blockIdx.x * 256 + threadIdx.x;
  if (e < NE) normv[e] = rsqrtf((float)cnt_u[src[e]] * (float)cnt_i[dst[e]]);
}

// ================= exclusive scan (3-pass) =================
__global__ __launch_bounds__(256) void scan_blocks(const int* __restrict__ cnt,
                                                   int* __restrict__ ofs,
                                                   int* __restrict__ partials, int n) {
  __shared__ int sm[256];
  int i = blockIdx.x * 256 + threadIdx.x;
  int v = (i < n) ? cnt[i] : 0;
  sm[threadIdx.x] = v;
  __syncthreads();
  for (int off = 1; off < 256; off <<= 1) {
    int t = (threadIdx.x >= off) ? sm[threadIdx.x - off] : 0;
    __syncthreads();
    sm[threadIdx.x] += t;
    __syncthreads();
  }
  if (i < n) ofs[i] = sm[threadIdx.x] - v;  // block-local exclusive
  if (threadIdx.x == 255) partials[blockIdx.x] = sm[255];
}

__global__ __launch_bounds__(1024) void scan_partials(int* __restrict__ partials, int nblocks) {
  __shared__ int sm[1024];
  int v = (threadIdx.x < nblocks) ? partials[threadIdx.x] : 0;
  sm[threadIdx.x] = v;
  __syncthreads();
  for (int off = 1; off < 1024; off <<= 1) {
    int t = (threadIdx.x >= off) ? sm[threadIdx.x - off] : 0;
    __syncthreads();
    sm[threadIdx.x] += t;
    __syncthreads();
  }
  if (threadIdx.x < nblocks) partials[threadIdx.x] = sm[threadIdx.x] - v;  // exclusive
}

__global__ __launch_bounds__(256) void add_offsets(int* __restrict__ ofs,
                                                   const int* __restrict__ partials,
                                                   int n, int total) {
  int i = blockIdx.x * 256 + threadIdx.x;
  if (i < n) ofs[i] += partials[i / 256];
  if (i == 0) ofs[n] = total;
}

__global__ __launch_bounds__(256) void copy_int(const int* __restrict__ a, int* __restrict__ b, int n) {
  int i = blockIdx.x * 256 + threadIdx.x;
  if (i < n) b[i] = a[i];
}

// ================= CSR placement =================
__global__ __launch_bounds__(256) void place_kernel(const int* __restrict__ src,
                                                    const int* __restrict__ dst,
                                                    const float* __restrict__ normv,
                                                    int* __restrict__ cur_u, int* __restrict__ cur_i,
                                                    int* __restrict__ by_src_dst, float* __restrict__ by_src_nrm,
                                                    int* __restrict__ by_dst_src, float* __restrict__ by_dst_nrm) {
  int e = blockIdx.x * 256 + threadIdx.x;
  if (e >= NE) return;
  int s = src[e], d = dst[e];
  float w = normv[e];
  int p = atomicAdd(&cur_u[s], 1);
  by_src_dst[p] = d;
  by_src_nrm[p] = w;
  int q = atomicAdd(&cur_i[d], 1);
  by_dst_src[q] = s;
  by_dst_nrm[q] = w;
}

// ================= g gather-sum: g[r] = sum_e nrm_e * h[nbr_e], c[r] = sum_e nrm_e =====
// wave per node; 4 lane-groups of 16, each group handles one edge per iter (float4/lane).
__global__ __launch_bounds__(256) void gatherg_kernel(const int* __restrict__ ofs,
                                                      const int* __restrict__ nbr,
                                                      const float* __restrict__ nrm,
                                                      const float* __restrict__ hsrc,
                                                      float* __restrict__ g,
                                                      float* __restrict__ c, int n) {
  const int lane = threadIdx.x & 63;
  const int w = threadIdx.x >> 6;
  const int j4 = lane & 15, grp = lane >> 4;
  const int nwaves = gridDim.x * 4;
  for (int r = blockIdx.x * 4 + w; r < n; r += nwaves) {
    const int lo = ofs[r], hiE = ofs[r + 1];
    float4 acc = {0.f, 0.f, 0.f, 0.f};
    float cs = 0.f;
    for (int k = lo + grp; k < hiE; k += 4) {
      const int idx = nbr[k];
      const float ww = nrm[k];
      const float4 v = *(const float4*)&hsrc[(size_t)idx * 64 + j4 * 4];
      acc.x += ww * v.x;
      acc.y += ww * v.y;
      acc.z += ww * v.z;
      acc.w += ww * v.w;
      cs += ww;
    }
#pragma unroll
    for (int m = 16; m < 64; m <<= 1) {
      acc.x += __shfl_xor(acc.x, m);
      acc.y += __shfl_xor(acc.y, m);
      acc.z += __shfl_xor(acc.z, m);
      acc.w += __shfl_xor(acc.w, m);
      cs += __shfl_xor(cs, m);
    }
    if (grp == 0) {
      *(float4*)&g[(size_t)r * 64 + j4 * 4] = acc;
      if (j4 == 0) c[r] = cs;
    }
  }
}

// ========== node: hnew = actnorm( g@W1 + (g.*hold)@W2 + c*(b1+b2) ) ==========
__global__ __launch_bounds__(256, 2) void node_kernel(const float* __restrict__ g,
                                                      const float* __restrict__ c,
                                                      const float* __restrict__ hold,
                                                      const float* __restrict__ W1,
                                                      const float* __restrict__ b1,
                                                      const float* __restrict__ W2,
                                                      const float* __restrict__ b2,
                                                      float* __restrict__ hnew, int n) {
  __shared__ float gs[4][64], ps[4][64];
  const int lane = threadIdx.x & 63;
  const int w = threadIdx.x >> 6;
  float w1c[64], w2c[64];
#pragma unroll
  for (int k = 0; k < 64; ++k) {
    w1c[k] = W1[k * 64 + lane];
    w2c[k] = W2[k * 64 + lane];
  }
  const float bv = b1[lane] + b2[lane];
  const int nwaves = gridDim.x * 4;
  for (int r = blockIdx.x * 4 + w; r < n; r += nwaves) {
    const float gv = g[(size_t)r * 64 + lane];
    const float hv = hold[(size_t)r * 64 + lane];
    gs[w][lane] = gv;
    ps[w][lane] = gv * hv;
    float a0 = 0.f, a1 = 0.f, a2 = 0.f, a3 = 0.f;
#pragma unroll
    for (int k = 0; k < 16; ++k) {
      const float4 G = *(const float4*)&gs[w][k * 4];
      const float4 P = *(const float4*)&ps[w][k * 4];
      a0 += G.x * w1c[4 * k + 0] + P.x * w2c[4 * k + 0];
      a1 += G.y * w1c[4 * k + 1] + P.y * w2c[4 * k + 1];
      a2 += G.z * w1c[4 * k + 2] + P.z * w2c[4 * k + 2];
      a3 += G.w * w1c[4 * k + 3] + P.w * w2c[4 * k + 3];
    }
    float v = (a0 + a1) + (a2 + a3) + c[r] * bv;
    v = (v > 0.f) ? v : 0.2f * v;
    float ss = v * v;
#pragma unroll
    for (int m = 1; m < 64; m <<= 1) ss += __shfl_xor(ss, m);
    hnew[(size_t)r * 64 + lane] = v / fmaxf(sqrtf(ss), 1e-12f);
  }
}

// ================= output gather =================
__global__ __launch_bounds__(256) void gather_kernel(const float* __restrict__ hu,
                                                     const float* __restrict__ hi,
                                                     const int* __restrict__ users,
                                                     const int* __restrict__ pos,
                                                     const int* __restrict__ neg,
                                                     float* __restrict__ out,
                                                     int stage) {
  int t = blockIdx.x * 256 + threadIdx.x;
  if (t >= 3 * NB * 64) return;
  int j = t & 63;
  int b = (t >> 6) & (NB - 1);
  int which = t / (NB * 64);
  int row = (which == 0) ? users[b] : ((which == 1) ? pos[b] : neg[b]);
  const float* h = (which == 0) ? hu : hi;
  out[(size_t)which * NB * 256 + (size_t)b * 256 + (size_t)stage * 64 + j] =
      h[(size_t)row * 64 + j];
}

extern "C" void kernel_launch(void* const* d_in, const int* in_sizes, int n_in,
                              void* d_out, int out_size, void* d_ws, size_t ws_size,
                              hipStream_t stream) {
  (void)in_sizes; (void)n_in; (void)out_size; (void)ws_size;
  const float* user_feat = (const float*)d_in[0];
  const float* item_feat = (const float*)d_in[1];
  const float* W1 = (const float*)d_in[2];
  const float* b1 = (const float*)d_in[3];
  const float* W2 = (const float*)d_in[4];
  const float* b2 = (const float*)d_in[5];
  const int* edge_src = (const int*)d_in[6];
  const int* edge_dst = (const int*)d_in[7];
  const int* users = (const int*)d_in[8];
  const int* pos_items = (const int*)d_in[9];
  const int* neg_items = (const int*)d_in[10];
  float* out = (float*)d_out;

  char* base = (char*)d_ws;
  size_t ofsz = 0;
  auto alloc = [&](size_t bytes) -> char* {
    char* r = base + ofsz;
    ofsz += (bytes + 1023) & ~(size_t)1023;
    return r;
  };
  // persistent
  int* ofs_u = (int*)alloc((NU + 1) * 4);
  int* ofs_i = (int*)alloc((NI + 1) * 4);
  int* by_src_dst = (int*)alloc((size_t)NE * 4);
  float* by_src_nrm = (float*)alloc((size_t)NE * 4);
  int* by_dst_src = (int*)alloc((size_t)NE * 4);
  float* by_dst_nrm = (float*)alloc((size_t)NE * 4);
  float* c_u = (float*)alloc((size_t)NU * 4);
  float* c_i = (float*)alloc((size_t)NI * 4);
  float* g_u = (float*)alloc((size_t)NU * 64 * 4);
  float* g_i = (float*)alloc((size_t)NI * 64 * 4);
  float* bufU0 = (float*)alloc((size_t)NU * 64 * 4);
  float* bufU1 = (float*)alloc((size_t)NU * 64 * 4);
  float* bufI0 = (float*)alloc((size_t)NI * 64 * 4);
  float* bufI1 = (float*)alloc((size_t)NI * 64 * 4);
  // setup temporaries aliased onto g_i (only used before first gatherg writes g_i)
  char* tmp = (char*)g_i;
  int* cnt_u = (int*)tmp;           tmp += ((NU * 4 + 1023) & ~1023);
  int* cnt_i = (int*)tmp;           tmp += ((NI * 4 + 1023) & ~1023);
  int* cur_u = (int*)tmp;           tmp += ((NU * 4 + 1023) & ~1023);
  int* cur_i = (int*)tmp;           tmp += ((NI * 4 + 1023) & ~1023);
  float* normv = (float*)tmp;       tmp += (((size_t)NE * 4 + 1023) & ~1023);
  int* partials = (int*)tmp;        tmp += 4096;

  float* bufU[2] = {bufU0, bufU1};
  float* bufI[2] = {bufI0, bufI1};

  // ---- build degrees, norms, CSR (both directions) ----
  hipMemsetAsync(cnt_u, 0, (size_t)NU * 4, stream);
  hipMemsetAsync(cnt_i, 0, (size_t)NI * 4, stream);
  hist_kernel<<<(NE + 255) / 256, 256, 0, stream>>>(edge_src, edge_dst, cnt_u, cnt_i);
  normv_kernel<<<(NE + 255) / 256, 256, 0, stream>>>(edge_src, edge_dst, cnt_u, cnt_i, normv);

  const int nbU = (NU + 255) / 256, nbI = (NI + 255) / 256;
  scan_blocks<<<nbU, 256, 0, stream>>>(cnt_u, ofs_u, partials, NU);
  scan_partials<<<1, 1024, 0, stream>>>(partials, nbU);
  add_offsets<<<nbU, 256, 0, stream>>>(ofs_u, partials, NU, NE);
  scan_blocks<<<nbI, 256, 0, stream>>>(cnt_i, ofs_i, partials, NI);
  scan_partials<<<1, 1024, 0, stream>>>(partials, nbI);
  add_offsets<<<nbI, 256, 0, stream>>>(ofs_i, partials, NI, NE);

  copy_int<<<nbU, 256, 0, stream>>>(ofs_u, cur_u, NU);
  copy_int<<<nbI, 256, 0, stream>>>(ofs_i, cur_i, NI);
  place_kernel<<<(NE + 255) / 256, 256, 0, stream>>>(edge_src, edge_dst, normv, cur_u, cur_i,
                                                     by_src_dst, by_src_nrm, by_dst_src, by_dst_nrm);

  // ---- stage 0 output ----
  gather_kernel<<<(3 * NB * 64 + 255) / 256, 256, 0, stream>>>(
      user_feat, item_feat, users, pos_items, neg_items, out, 0);

  // ---- layers ----
  const float* hu = user_feat;
  const float* hi = item_feat;
  for (int l = 0; l < 3; ++l) {
    float* hu_new = bufU[l & 1];
    float* hi_new = bufI[l & 1];
    gatherg_kernel<<<(NI + 3) / 4, 256, 0, stream>>>(ofs_i, by_dst_src, by_dst_nrm, hu, g_i, c_i, NI);
    gatherg_kernel<<<(NU + 3) / 4, 256, 0, stream>>>(ofs_u, by_src_dst, by_src_nrm, hi, g_u, c_u, NU);
    node_kernel<<<1024, 256, 0, stream>>>(g_i, c_i, hi, W1 + l * 4096, b1 + l * 64,
                                          W2 + l * 4096, b2 + l * 64, hi_new, NI);
    node_kernel<<<1024, 256, 0, stream>>>(g_u, c_u, hu, W1 + l * 4096, b1 + l * 64,
                                          W2 + l * 4096, b2 + l * 64, hu_new, NU);
    gather_kernel<<<(3 * NB * 64 + 255) / 256, 256, 0, stream>>>(
        hu_new, hi_new, users, pos_items, neg_items, out, l + 1);
    hu = hu_new;
    hi = hi_new;
  }
}

// Round 3
// 746.553 us; speedup vs baseline: 2.4802x; 1.6787x over previous
//
#include <hip/hip_runtime.h>

#define NU 100000
#define NI 200000
#define NE 1000000
#define NB 4096

typedef __attribute__((ext_vector_type(8))) short bf16x8;
typedef __attribute__((ext_vector_type(4))) float f32x4;

static __device__ __forceinline__ short f2bf(float f) {
  unsigned u = __builtin_bit_cast(unsigned, f);
  unsigned r = (u + 0x7fffu + ((u >> 16) & 1u)) >> 16;
  return (short)r;
}

// ================= setup: degree histogram =================
__global__ __launch_bounds__(256) void hist_kernel(const int* __restrict__ src,
                                                   const int* __restrict__ dst,
                                                   int* __restrict__ cnt_u,
                                                   int* __restrict__ cnt_i) {
  int e = blockIdx.x * 256 + threadIdx.x;
  if (e < NE) {
    atomicAdd(&cnt_u[src[e]], 1);
    atomicAdd(&cnt_i[dst[e]], 1);
  }
}

__global__ __launch_bounds__(256) void normv_kernel(const int* __restrict__ src,
                                                    const int* __restrict__ dst,
                                                    const int* __restrict__ cnt_u,
                                                    const int* __restrict__ cnt_i,
                                                    float* __restrict__ normv) {
  int e = blockIdx.x * 256 + threadIdx.x;
  if (e < NE) normv[e] = rsqrtf((float)cnt_u[src[e]] * (float)cnt_i[dst[e]]);
}

// ================= exclusive scan (3-pass) =================
__global__ __launch_bounds__(256) void scan_blocks(const int* __restrict__ cnt,
                                                   int* __restrict__ ofs,
                                                   int* __restrict__ partials, int n) {
  __shared__ int sm[256];
  int i = blockIdx.x * 256 + threadIdx.x;
  int v = (i < n) ? cnt[i] : 0;
  sm[threadIdx.x] = v;
  __syncthreads();
  for (int off = 1; off < 256; off <<= 1) {
    int t = (threadIdx.x >= off) ? sm[threadIdx.x - off] : 0;
    __syncthreads();
    sm[threadIdx.x] += t;
    __syncthreads();
  }
  if (i < n) ofs[i] = sm[threadIdx.x] - v;  // block-local exclusive
  if (threadIdx.x == 255) partials[blockIdx.x] = sm[255];
}

__global__ __launch_bounds__(1024) void scan_partials(int* __restrict__ partials, int nblocks) {
  __shared__ int sm[1024];
  int v = (threadIdx.x < nblocks) ? partials[threadIdx.x] : 0;
  sm[threadIdx.x] = v;
  __syncthreads();
  for (int off = 1; off < 1024; off <<= 1) {
    int t = (threadIdx.x >= off) ? sm[threadIdx.x - off] : 0;
    __syncthreads();
    sm[threadIdx.x] += t;
    __syncthreads();
  }
  if (threadIdx.x < nblocks) partials[threadIdx.x] = sm[threadIdx.x] - v;  // exclusive
}

__global__ __launch_bounds__(256) void add_offsets(int* __restrict__ ofs,
                                                   const int* __restrict__ partials,
                                                   int n, int total) {
  int i = blockIdx.x * 256 + threadIdx.x;
  if (i < n) ofs[i] += partials[i / 256];
  if (i == 0) ofs[n] = total;
}

__global__ __launch_bounds__(256) void copy_int(const int* __restrict__ a, int* __restrict__ b, int n) {
  int i = blockIdx.x * 256 + threadIdx.x;
  if (i < n) b[i] = a[i];
}

// ================= CSR placement =================
__global__ __launch_bounds__(256) void place_kernel(const int* __restrict__ src,
                                                    const int* __restrict__ dst,
                                                    const float* __restrict__ normv,
                                                    int* __restrict__ cur_u, int* __restrict__ cur_i,
                                                    int* __restrict__ by_src_dst, float* __restrict__ by_src_nrm,
                                                    int* __restrict__ by_dst_src, float* __restrict__ by_dst_nrm) {
  int e = blockIdx.x * 256 + threadIdx.x;
  if (e >= NE) return;
  int s = src[e], d = dst[e];
  float w = normv[e];
  int p = atomicAdd(&cur_u[s], 1);
  by_src_dst[p] = d;
  by_src_nrm[p] = w;
  int q = atomicAdd(&cur_i[d], 1);
  by_dst_src[q] = s;
  by_dst_nrm[q] = w;
}

// ================= g gather-sum =================
__global__ __launch_bounds__(256) void gatherg_kernel(const int* __restrict__ ofs,
                                                      const int* __restrict__ nbr,
                                                      const float* __restrict__ nrm,
                                                      const float* __restrict__ hsrc,
                                                      float* __restrict__ g,
                                                      float* __restrict__ c, int n) {
  const int lane = threadIdx.x & 63;
  const int w = threadIdx.x >> 6;
  const int j4 = lane & 15, grp = lane >> 4;
  const int nwaves = gridDim.x * 4;
  for (int r = blockIdx.x * 4 + w; r < n; r += nwaves) {
    const int lo = ofs[r], hiE = ofs[r + 1];
    float4 acc = {0.f, 0.f, 0.f, 0.f};
    float cs = 0.f;
    for (int k = lo + grp; k < hiE; k += 4) {
      const int idx = nbr[k];
      const float ww = nrm[k];
      const float4 v = *(const float4*)&hsrc[(size_t)idx * 64 + j4 * 4];
      acc.x += ww * v.x;
      acc.y += ww * v.y;
      acc.z += ww * v.z;
      acc.w += ww * v.w;
      cs += ww;
    }
#pragma unroll
    for (int m = 16; m < 64; m <<= 1) {
      acc.x += __shfl_xor(acc.x, m);
      acc.y += __shfl_xor(acc.y, m);
      acc.z += __shfl_xor(acc.z, m);
      acc.w += __shfl_xor(acc.w, m);
      cs += __shfl_xor(cs, m);
    }
    if (grp == 0) {
      *(float4*)&g[(size_t)r * 64 + j4 * 4] = acc;
      if (j4 == 0) c[r] = cs;
    }
  }
}

// ========== node via MFMA: hnew = actnorm( g@W1 + (g.*hold)@W2 + c*(b1+b2) ) ==========
// one wave per 16-row tile; 16x16x32 bf16 MFMA, f32 accumulate.
// A frag: row=l&15, k=8*(l>>4)+j ; B frag: col=l&15, k=8*(l>>4)+j ;
// D frag: col=l&15, row=4*(l>>4)+reg.
__global__ __launch_bounds__(256) void node_mfma_kernel(const float* __restrict__ g,
                                                        const float* __restrict__ c,
                                                        const float* __restrict__ hold,
                                                        const float* __restrict__ W1,
                                                        const float* __restrict__ b1,
                                                        const float* __restrict__ W2,
                                                        const float* __restrict__ b2,
                                                        float* __restrict__ hnew, int ntiles) {
  const int lane = threadIdx.x & 63;
  const int row16 = lane & 15;
  const int kgrp = lane >> 4;  // 0..3
  const int wid = (blockIdx.x * 256 + threadIdx.x) >> 6;
  const int nwaves = (gridDim.x * 256) >> 6;

  // weight fragments (bf16), register-resident: 64 VGPRs total
  bf16x8 w1f[4][2], w2f[4][2];
#pragma unroll
  for (int nb = 0; nb < 4; ++nb)
#pragma unroll
    for (int kb = 0; kb < 2; ++kb) {
      const int n = nb * 16 + row16;
      const int k0 = kb * 32 + kgrp * 8;
      bf16x8 t1, t2;
#pragma unroll
      for (int j = 0; j < 8; ++j) {
        t1[j] = f2bf(W1[(k0 + j) * 64 + n]);
        t2[j] = f2bf(W2[(k0 + j) * 64 + n]);
      }
      w1f[nb][kb] = t1;
      w2f[nb][kb] = t2;
    }
  float bsum[4];
#pragma unroll
  for (int nb = 0; nb < 4; ++nb) bsum[nb] = b1[nb * 16 + row16] + b2[nb * 16 + row16];

  for (int t = wid; t < ntiles; t += nwaves) {
    const int r0 = t * 16;
    const float* gp = g + (size_t)(r0 + row16) * 64 + kgrp * 8;
    const float* hp = hold + (size_t)(r0 + row16) * 64 + kgrp * 8;
    bf16x8 ag[2], ap[2];
#pragma unroll
    for (int kb = 0; kb < 2; ++kb) {
      const float4 g0 = *(const float4*)(gp + kb * 32);
      const float4 g1 = *(const float4*)(gp + kb * 32 + 4);
      const float4 h0 = *(const float4*)(hp + kb * 32);
      const float4 h1 = *(const float4*)(hp + kb * 32 + 4);
      bf16x8 a, p;
      a[0] = f2bf(g0.x); a[1] = f2bf(g0.y); a[2] = f2bf(g0.z); a[3] = f2bf(g0.w);
      a[4] = f2bf(g1.x); a[5] = f2bf(g1.y); a[6] = f2bf(g1.z); a[7] = f2bf(g1.w);
      p[0] = f2bf(g0.x * h0.x); p[1] = f2bf(g0.y * h0.y);
      p[2] = f2bf(g0.z * h0.z); p[3] = f2bf(g0.w * h0.w);
      p[4] = f2bf(g1.x * h1.x); p[5] = f2bf(g1.y * h1.y);
      p[6] = f2bf(g1.z * h1.z); p[7] = f2bf(g1.w * h1.w);
      ag[kb] = a;
      ap[kb] = p;
    }
    f32x4 acc[4];
#pragma unroll
    for (int nb = 0; nb < 4; ++nb) acc[nb] = (f32x4){0.f, 0.f, 0.f, 0.f};
#pragma unroll
    for (int nb = 0; nb < 4; ++nb)
#pragma unroll
      for (int kb = 0; kb < 2; ++kb) {
        acc[nb] = __builtin_amdgcn_mfma_f32_16x16x32_bf16(ag[kb], w1f[nb][kb], acc[nb], 0, 0, 0);
        acc[nb] = __builtin_amdgcn_mfma_f32_16x16x32_bf16(ap[kb], w2f[nb][kb], acc[nb], 0, 0, 0);
      }
    float cv[4];
#pragma unroll
    for (int reg = 0; reg < 4; ++reg) cv[reg] = c[r0 + kgrp * 4 + reg];
    float v[4][4];
    float ss[4] = {0.f, 0.f, 0.f, 0.f};
#pragma unroll
    for (int nb = 0; nb < 4; ++nb)
#pragma unroll
      for (int reg = 0; reg < 4; ++reg) {
        float x = acc[nb][reg] + cv[reg] * bsum[nb];
        x = (x > 0.f) ? x : 0.2f * x;
        v[nb][reg] = x;
        ss[reg] += x * x;
      }
#pragma unroll
    for (int m = 1; m < 16; m <<= 1)
#pragma unroll
      for (int reg = 0; reg < 4; ++reg) ss[reg] += __shfl_xor(ss[reg], m);
    float inv[4];
#pragma unroll
    for (int reg = 0; reg < 4; ++reg) inv[reg] = 1.0f / fmaxf(sqrtf(ss[reg]), 1e-12f);
#pragma unroll
    for (int reg = 0; reg < 4; ++reg) {
      const size_t rowbase = (size_t)(r0 + kgrp * 4 + reg) * 64;
#pragma unroll
      for (int nb = 0; nb < 4; ++nb)
        hnew[rowbase + nb * 16 + row16] = v[nb][reg] * inv[reg];
    }
  }
}

// ================= output gather =================
__global__ __launch_bounds__(256) void gather_kernel(const float* __restrict__ hu,
                                                     const float* __restrict__ hi,
                                                     const int* __restrict__ users,
                                                     const int* __restrict__ pos,
                                                     const int* __restrict__ neg,
                                                     float* __restrict__ out,
                                                     int stage) {
  int t = blockIdx.x * 256 + threadIdx.x;
  if (t >= 3 * NB * 64) return;
  int j = t & 63;
  int b = (t >> 6) & (NB - 1);
  int which = t / (NB * 64);
  int row = (which == 0) ? users[b] : ((which == 1) ? pos[b] : neg[b]);
  const float* h = (which == 0) ? hu : hi;
  out[(size_t)which * NB * 256 + (size_t)b * 256 + (size_t)stage * 64 + j] =
      h[(size_t)row * 64 + j];
}

extern "C" void kernel_launch(void* const* d_in, const int* in_sizes, int n_in,
                              void* d_out, int out_size, void* d_ws, size_t ws_size,
                              hipStream_t stream) {
  (void)in_sizes; (void)n_in; (void)out_size; (void)ws_size;
  const float* user_feat = (const float*)d_in[0];
  const float* item_feat = (const float*)d_in[1];
  const float* W1 = (const float*)d_in[2];
  const float* b1 = (const float*)d_in[3];
  const float* W2 = (const float*)d_in[4];
  const float* b2 = (const float*)d_in[5];
  const int* edge_src = (const int*)d_in[6];
  const int* edge_dst = (const int*)d_in[7];
  const int* users = (const int*)d_in[8];
  const int* pos_items = (const int*)d_in[9];
  const int* neg_items = (const int*)d_in[10];
  float* out = (float*)d_out;

  char* base = (char*)d_ws;
  size_t ofsz = 0;
  auto alloc = [&](size_t bytes) -> char* {
    char* r = base + ofsz;
    ofsz += (bytes + 1023) & ~(size_t)1023;
    return r;
  };
  int* ofs_u = (int*)alloc((NU + 1) * 4);
  int* ofs_i = (int*)alloc((NI + 1) * 4);
  int* by_src_dst = (int*)alloc((size_t)NE * 4);
  float* by_src_nrm = (float*)alloc((size_t)NE * 4);
  int* by_dst_src = (int*)alloc((size_t)NE * 4);
  float* by_dst_nrm = (float*)alloc((size_t)NE * 4);
  float* c_u = (float*)alloc((size_t)NU * 4);
  float* c_i = (float*)alloc((size_t)NI * 4);
  float* g_u = (float*)alloc((size_t)NU * 64 * 4);
  float* g_i = (float*)alloc((size_t)NI * 64 * 4);
  float* bufU0 = (float*)alloc((size_t)NU * 64 * 4);
  float* bufU1 = (float*)alloc((size_t)NU * 64 * 4);
  float* bufI0 = (float*)alloc((size_t)NI * 64 * 4);
  float* bufI1 = (float*)alloc((size_t)NI * 64 * 4);
  // setup temporaries aliased onto g_i (dead before first gatherg writes g_i)
  char* tmp = (char*)g_i;
  int* cnt_u = (int*)tmp;           tmp += ((NU * 4 + 1023) & ~1023);
  int* cnt_i = (int*)tmp;           tmp += ((NI * 4 + 1023) & ~1023);
  int* cur_u = (int*)tmp;           tmp += ((NU * 4 + 1023) & ~1023);
  int* cur_i = (int*)tmp;           tmp += ((NI * 4 + 1023) & ~1023);
  float* normv = (float*)tmp;       tmp += (((size_t)NE * 4 + 1023) & ~1023);
  int* partials = (int*)tmp;        tmp += 4096;

  float* bufU[2] = {bufU0, bufU1};
  float* bufI[2] = {bufI0, bufI1};

  hipMemsetAsync(cnt_u, 0, (size_t)NU * 4, stream);
  hipMemsetAsync(cnt_i, 0, (size_t)NI * 4, stream);
  hist_kernel<<<(NE + 255) / 256, 256, 0, stream>>>(edge_src, edge_dst, cnt_u, cnt_i);
  normv_kernel<<<(NE + 255) / 256, 256, 0, stream>>>(edge_src, edge_dst, cnt_u, cnt_i, normv);

  const int nbU = (NU + 255) / 256, nbI = (NI + 255) / 256;
  scan_blocks<<<nbU, 256, 0, stream>>>(cnt_u, ofs_u, partials, NU);
  scan_partials<<<1, 1024, 0, stream>>>(partials, nbU);
  add_offsets<<<nbU, 256, 0, stream>>>(ofs_u, partials, NU, NE);
  scan_blocks<<<nbI, 256, 0, stream>>>(cnt_i, ofs_i, partials, NI);
  scan_partials<<<1, 1024, 0, stream>>>(partials, nbI);
  add_offsets<<<nbI, 256, 0, stream>>>(ofs_i, partials, NI, NE);

  copy_int<<<nbU, 256, 0, stream>>>(ofs_u, cur_u, NU);
  copy_int<<<nbI, 256, 0, stream>>>(ofs_i, cur_i, NI);
  place_kernel<<<(NE + 255) / 256, 256, 0, stream>>>(edge_src, edge_dst, normv, cur_u, cur_i,
                                                     by_src_dst, by_src_nrm, by_dst_src, by_dst_nrm);

  gather_kernel<<<(3 * NB * 64 + 255) / 256, 256, 0, stream>>>(
      user_feat, item_feat, users, pos_items, neg_items, out, 0);

  const float* hu = user_feat;
  const float* hi = item_feat;
  for (int l = 0; l < 3; ++l) {
    float* hu_new = bufU[l & 1];
    float* hi_new = bufI[l & 1];
    gatherg_kernel<<<(NI + 3) / 4, 256, 0, stream>>>(ofs_i, by_dst_src, by_dst_nrm, hu, g_i, c_i, NI);
    gatherg_kernel<<<(NU + 3) / 4, 256, 0, stream>>>(ofs_u, by_src_dst, by_src_nrm, hi, g_u, c_u, NU);
    node_mfma_kernel<<<1024, 256, 0, stream>>>(g_i, c_i, hi, W1 + l * 4096, b1 + l * 64,
                                               W2 + l * 4096, b2 + l * 64, hi_new, NI / 16);
    node_mfma_kernel<<<1024, 256, 0, stream>>>(g_u, c_u, hu, W1 + l * 4096, b1 + l * 64,
                                               W2 + l * 4096, b2 + l * 64, hu_new, NU / 16);
    gather_kernel<<<(3 * NB * 64 + 255) / 256, 256, 0, stream>>>(
        hu_new, hi_new, users, pos_items, neg_items, out, l + 1);
    hu = hu_new;
    hi = hi_new;
  }
}

// Round 4
// 669.202 us; speedup vs baseline: 2.7668x; 1.1156x over previous
//
#include <hip/hip_runtime.h>

#define NU 100000
#define NI 200000
#define NE 1000000
#define NB 4096

typedef __attribute__((ext_vector_type(8))) short bf16x8;
typedef __attribute__((ext_vector_type(4))) float f32x4;
typedef __attribute__((ext_vector_type(8))) unsigned short u16x8;

static __device__ __forceinline__ short f2bf(float f) {
  unsigned u = __builtin_bit_cast(unsigned, f);
  unsigned r = (u + 0x7fffu + ((u >> 16) & 1u)) >> 16;
  return (short)r;
}
static __device__ __forceinline__ float bf2f(unsigned short u) {
  return __builtin_bit_cast(float, ((unsigned)u) << 16);
}

// ================= setup: degree histogram =================
__global__ __launch_bounds__(256) void hist_kernel(const int* __restrict__ src,
                                                   const int* __restrict__ dst,
                                                   int* __restrict__ cnt_u,
                                                   int* __restrict__ cnt_i) {
  int e = blockIdx.x * 256 + threadIdx.x;
  if (e < NE) {
    atomicAdd(&cnt_u[src[e]], 1);
    atomicAdd(&cnt_i[dst[e]], 1);
  }
}

// ================= exclusive scan (3-pass) =================
__global__ __launch_bounds__(256) void scan_blocks(const int* __restrict__ cnt,
                                                   int* __restrict__ ofs,
                                                   int* __restrict__ partials, int n) {
  __shared__ int sm[256];
  int i = blockIdx.x * 256 + threadIdx.x;
  int v = (i < n) ? cnt[i] : 0;
  sm[threadIdx.x] = v;
  __syncthreads();
  for (int off = 1; off < 256; off <<= 1) {
    int t = (threadIdx.x >= off) ? sm[threadIdx.x - off] : 0;
    __syncthreads();
    sm[threadIdx.x] += t;
    __syncthreads();
  }
  if (i < n) ofs[i] = sm[threadIdx.x] - v;
  if (threadIdx.x == 255) partials[blockIdx.x] = sm[255];
}

__global__ __launch_bounds__(1024) void scan_partials(int* __restrict__ partials, int nblocks) {
  __shared__ int sm[1024];
  int v = (threadIdx.x < nblocks) ? partials[threadIdx.x] : 0;
  sm[threadIdx.x] = v;
  __syncthreads();
  for (int off = 1; off < 1024; off <<= 1) {
    int t = (threadIdx.x >= off) ? sm[threadIdx.x - off] : 0;
    __syncthreads();
    sm[threadIdx.x] += t;
    __syncthreads();
  }
  if (threadIdx.x < nblocks) partials[threadIdx.x] = sm[threadIdx.x] - v;
}

__global__ __launch_bounds__(256) void add_offsets(int* __restrict__ ofs,
                                                   const int* __restrict__ partials,
                                                   int n, int total) {
  int i = blockIdx.x * 256 + threadIdx.x;
  if (i < n) ofs[i] += partials[i / 256];
  if (i == 0) ofs[n] = total;
}

__global__ __launch_bounds__(256) void copy_int(const int* __restrict__ a, int* __restrict__ b, int n) {
  int i = blockIdx.x * 256 + threadIdx.x;
  if (i < n) b[i] = a[i];
}

// ================= CSR placement: payload = (nbr, rs_nbr) packed 8B =================
__global__ __launch_bounds__(256) void place_kernel(const int* __restrict__ src,
                                                    const int* __restrict__ dst,
                                                    const int* __restrict__ cnt_u,
                                                    const int* __restrict__ cnt_i,
                                                    int* __restrict__ cur_u, int* __restrict__ cur_i,
                                                    int2* __restrict__ by_src,
                                                    int2* __restrict__ by_dst) {
  int e = blockIdx.x * 256 + threadIdx.x;
  if (e >= NE) return;
  int s = src[e], d = dst[e];
  float rsu = rsqrtf((float)cnt_u[s]);
  float rsi = rsqrtf((float)cnt_i[d]);
  int p = atomicAdd(&cur_u[s], 1);
  by_src[p] = make_int2(d, __builtin_bit_cast(int, rsi));
  int q = atomicAdd(&cur_i[d], 1);
  by_dst[q] = make_int2(s, __builtin_bit_cast(int, rsu));
}

// ================= f32 -> bf16 conversion =================
__global__ __launch_bounds__(256) void conv_kernel(const float* __restrict__ in,
                                                   unsigned short* __restrict__ outp, int n4) {
  int i = blockIdx.x * 256 + threadIdx.x;
  if (i < n4) {
    float4 v = *(const float4*)&in[i * 4];
    ushort4 o;
    o.x = (unsigned short)f2bf(v.x);
    o.y = (unsigned short)f2bf(v.y);
    o.z = (unsigned short)f2bf(v.z);
    o.w = (unsigned short)f2bf(v.w);
    *(ushort4*)&outp[i * 4] = o;
  }
}

// ================= g gather-sum over bf16 h =================
// wave: 8 edge-groups x 8 lanes; lane j8 owns cols [8*j8, 8*j8+8); 16B ushort8 loads.
// g[r] = rs_r * sum_e w_e * h[nbr_e];  c[r] = rs_r * sum_e w_e
__global__ __launch_bounds__(256) void gatherg_kernel(const int* __restrict__ ofs,
                                                      const int2* __restrict__ pay,
                                                      const unsigned short* __restrict__ hsrc,
                                                      float* __restrict__ g,
                                                      float* __restrict__ c, int n) {
  const int lane = threadIdx.x & 63;
  const int w = threadIdx.x >> 6;
  const int j8 = lane & 7, grp = lane >> 3;
  const int nwaves = gridDim.x * 4;
  for (int r = blockIdx.x * 4 + w; r < n; r += nwaves) {
    const int lo = ofs[r], hiE = ofs[r + 1];
    float acc[8] = {0.f, 0.f, 0.f, 0.f, 0.f, 0.f, 0.f, 0.f};
    float cs = 0.f;
    for (int k = lo + grp; k < hiE; k += 8) {
      const int2 pw = pay[k];
      const float ww = __builtin_bit_cast(float, pw.y);
      const u16x8 hv = *(const u16x8*)(hsrc + (size_t)pw.x * 64 + j8 * 8);
#pragma unroll
      for (int j = 0; j < 8; ++j) acc[j] += ww * bf2f(hv[j]);
      cs += ww;
    }
#pragma unroll
    for (int m = 8; m < 64; m <<= 1) {
#pragma unroll
      for (int j = 0; j < 8; ++j) acc[j] += __shfl_xor(acc[j], m);
      cs += __shfl_xor(cs, m);
    }
    if (grp == 0) {
      const float rsn = (hiE > lo) ? rsqrtf((float)(hiE - lo)) : 0.f;
      float4 o0 = {acc[0] * rsn, acc[1] * rsn, acc[2] * rsn, acc[3] * rsn};
      float4 o1 = {acc[4] * rsn, acc[5] * rsn, acc[6] * rsn, acc[7] * rsn};
      *(float4*)&g[(size_t)r * 64 + j8 * 8] = o0;
      *(float4*)&g[(size_t)r * 64 + j8 * 8 + 4] = o1;
      if (j8 == 0) c[r] = cs * rsn;
    }
  }
}

// ========== node via MFMA: hnew = actnorm( g@W1 + (g.*hold)@W2 + c*(b1+b2) ) ==========
__global__ __launch_bounds__(256) void node_mfma_kernel(const float* __restrict__ g,
                                                        const float* __restrict__ c,
                                                        const unsigned short* __restrict__ hold,
                                                        const float* __restrict__ W1,
                                                        const float* __restrict__ b1,
                                                        const float* __restrict__ W2,
                                                        const float* __restrict__ b2,
                                                        unsigned short* __restrict__ hnew, int ntiles) {
  const int lane = threadIdx.x & 63;
  const int row16 = lane & 15;
  const int kgrp = lane >> 4;  // 0..3
  const int wid = (blockIdx.x * 256 + threadIdx.x) >> 6;
  const int nwaves = (gridDim.x * 256) >> 6;

  bf16x8 w1f[4][2], w2f[4][2];
#pragma unroll
  for (int nb = 0; nb < 4; ++nb)
#pragma unroll
    for (int kb = 0; kb < 2; ++kb) {
      const int n = nb * 16 + row16;
      const int k0 = kb * 32 + kgrp * 8;
      bf16x8 t1, t2;
#pragma unroll
      for (int j = 0; j < 8; ++j) {
        t1[j] = f2bf(W1[(k0 + j) * 64 + n]);
        t2[j] = f2bf(W2[(k0 + j) * 64 + n]);
      }
      w1f[nb][kb] = t1;
      w2f[nb][kb] = t2;
    }
  float bsum[4];
#pragma unroll
  for (int nb = 0; nb < 4; ++nb) bsum[nb] = b1[nb * 16 + row16] + b2[nb * 16 + row16];

  for (int t = wid; t < ntiles; t += nwaves) {
    const int r0 = t * 16;
    const float* gp = g + (size_t)(r0 + row16) * 64 + kgrp * 8;
    const unsigned short* hp = hold + (size_t)(r0 + row16) * 64 + kgrp * 8;
    bf16x8 ag[2], ap[2];
#pragma unroll
    for (int kb = 0; kb < 2; ++kb) {
      const float4 g0 = *(const float4*)(gp + kb * 32);
      const float4 g1 = *(const float4*)(gp + kb * 32 + 4);
      const u16x8 hv = *(const u16x8*)(hp + kb * 32);
      bf16x8 a, p;
      a[0] = f2bf(g0.x); a[1] = f2bf(g0.y); a[2] = f2bf(g0.z); a[3] = f2bf(g0.w);
      a[4] = f2bf(g1.x); a[5] = f2bf(g1.y); a[6] = f2bf(g1.z); a[7] = f2bf(g1.w);
      p[0] = f2bf(g0.x * bf2f(hv[0])); p[1] = f2bf(g0.y * bf2f(hv[1]));
      p[2] = f2bf(g0.z * bf2f(hv[2])); p[3] = f2bf(g0.w * bf2f(hv[3]));
      p[4] = f2bf(g1.x * bf2f(hv[4])); p[5] = f2bf(g1.y * bf2f(hv[5]));
      p[6] = f2bf(g1.z * bf2f(hv[6])); p[7] = f2bf(g1.w * bf2f(hv[7]));
      ag[kb] = a;
      ap[kb] = p;
    }
    f32x4 acc[4];
#pragma unroll
    for (int nb = 0; nb < 4; ++nb) acc[nb] = (f32x4){0.f, 0.f, 0.f, 0.f};
#pragma unroll
    for (int nb = 0; nb < 4; ++nb)
#pragma unroll
      for (int kb = 0; kb < 2; ++kb) {
        acc[nb] = __builtin_amdgcn_mfma_f32_16x16x32_bf16(ag[kb], w1f[nb][kb], acc[nb], 0, 0, 0);
        acc[nb] = __builtin_amdgcn_mfma_f32_16x16x32_bf16(ap[kb], w2f[nb][kb], acc[nb], 0, 0, 0);
      }
    float cv[4];
#pragma unroll
    for (int reg = 0; reg < 4; ++reg) cv[reg] = c[r0 + kgrp * 4 + reg];
    float v[4][4];
    float ss[4] = {0.f, 0.f, 0.f, 0.f};
#pragma unroll
    for (int nb = 0; nb < 4; ++nb)
#pragma unroll
      for (int reg = 0; reg < 4; ++reg) {
        float x = acc[nb][reg] + cv[reg] * bsum[nb];
        x = (x > 0.f) ? x : 0.2f * x;
        v[nb][reg] = x;
        ss[reg] += x * x;
      }
#pragma unroll
    for (int m = 1; m < 16; m <<= 1)
#pragma unroll
      for (int reg = 0; reg < 4; ++reg) ss[reg] += __shfl_xor(ss[reg], m);
    float inv[4];
#pragma unroll
    for (int reg = 0; reg < 4; ++reg) inv[reg] = 1.0f / fmaxf(sqrtf(ss[reg]), 1e-12f);
#pragma unroll
    for (int reg = 0; reg < 4; ++reg) {
      const size_t rowbase = (size_t)(r0 + kgrp * 4 + reg) * 64;
#pragma unroll
      for (int nb = 0; nb < 4; ++nb)
        hnew[rowbase + nb * 16 + row16] = (unsigned short)f2bf(v[nb][reg] * inv[reg]);
    }
  }
}

// ================= output gathers =================
__global__ __launch_bounds__(256) void gather_f32_kernel(const float* __restrict__ hu,
                                                         const float* __restrict__ hi,
                                                         const int* __restrict__ users,
                                                         const int* __restrict__ pos,
                                                         const int* __restrict__ neg,
                                                         float* __restrict__ out) {
  int t = blockIdx.x * 256 + threadIdx.x;
  if (t >= 3 * NB * 64) return;
  int j = t & 63;
  int b = (t >> 6) & (NB - 1);
  int which = t / (NB * 64);
  int row = (which == 0) ? users[b] : ((which == 1) ? pos[b] : neg[b]);
  const float* h = (which == 0) ? hu : hi;
  out[(size_t)which * NB * 256 + (size_t)b * 256 + j] = h[(size_t)row * 64 + j];
}

__global__ __launch_bounds__(256) void gather_bf_kernel(const unsigned short* __restrict__ hu,
                                                        const unsigned short* __restrict__ hi,
                                                        const int* __restrict__ users,
                                                        const int* __restrict__ pos,
                                                        const int* __restrict__ neg,
                                                        float* __restrict__ out, int stage) {
  int t = blockIdx.x * 256 + threadIdx.x;
  if (t >= 3 * NB * 64) return;
  int j = t & 63;
  int b = (t >> 6) & (NB - 1);
  int which = t / (NB * 64);
  int row = (which == 0) ? users[b] : ((which == 1) ? pos[b] : neg[b]);
  const unsigned short* h = (which == 0) ? hu : hi;
  out[(size_t)which * NB * 256 + (size_t)b * 256 + (size_t)stage * 64 + j] =
      bf2f(h[(size_t)row * 64 + j]);
}

extern "C" void kernel_launch(void* const* d_in, const int* in_sizes, int n_in,
                              void* d_out, int out_size, void* d_ws, size_t ws_size,
                              hipStream_t stream) {
  (void)in_sizes; (void)n_in; (void)out_size; (void)ws_size;
  const float* user_feat = (const float*)d_in[0];
  const float* item_feat = (const float*)d_in[1];
  const float* W1 = (const float*)d_in[2];
  const float* b1 = (const float*)d_in[3];
  const float* W2 = (const float*)d_in[4];
  const float* b2 = (const float*)d_in[5];
  const int* edge_src = (const int*)d_in[6];
  const int* edge_dst = (const int*)d_in[7];
  const int* users = (const int*)d_in[8];
  const int* pos_items = (const int*)d_in[9];
  const int* neg_items = (const int*)d_in[10];
  float* out = (float*)d_out;

  char* base = (char*)d_ws;
  size_t ofsz = 0;
  auto alloc = [&](size_t bytes) -> char* {
    char* r = base + ofsz;
    ofsz += (bytes + 1023) & ~(size_t)1023;
    return r;
  };
  int* ofs_u = (int*)alloc((NU + 1) * 4);
  int* ofs_i = (int*)alloc((NI + 1) * 4);
  int2* by_src = (int2*)alloc((size_t)NE * 8);
  int2* by_dst = (int2*)alloc((size_t)NE * 8);
  float* c_u = (float*)alloc((size_t)NU * 4);
  float* c_i = (float*)alloc((size_t)NI * 4);
  float* g_u = (float*)alloc((size_t)NU * 64 * 4);
  float* g_i = (float*)alloc((size_t)NI * 64 * 4);
  unsigned short* hbU0 = (unsigned short*)alloc((size_t)NU * 64 * 2);
  unsigned short* hbU1 = (unsigned short*)alloc((size_t)NU * 64 * 2);
  unsigned short* hbI0 = (unsigned short*)alloc((size_t)NI * 64 * 2);
  unsigned short* hbI1 = (unsigned short*)alloc((size_t)NI * 64 * 2);
  // setup temporaries aliased onto g_i (dead before first gatherg writes g_i)
  char* tmp = (char*)g_i;
  int* cnt_u = (int*)tmp;     tmp += ((NU * 4 + 1023) & ~1023);
  int* cnt_i = (int*)tmp;     tmp += ((NI * 4 + 1023) & ~1023);
  int* cur_u = (int*)tmp;     tmp += ((NU * 4 + 1023) & ~1023);
  int* cur_i = (int*)tmp;     tmp += ((NI * 4 + 1023) & ~1023);
  int* partials = (int*)tmp;  tmp += 4096;

  unsigned short* bufU[2] = {hbU1, hbU0};  // layer l writes bufU[l&1^... see flow below
  unsigned short* bufI[2] = {hbI1, hbI0};

  hipMemsetAsync(cnt_u, 0, (size_t)NU * 4, stream);
  hipMemsetAsync(cnt_i, 0, (size_t)NI * 4, stream);
  hist_kernel<<<(NE + 255) / 256, 256, 0, stream>>>(edge_src, edge_dst, cnt_u, cnt_i);

  const int nbU = (NU + 255) / 256, nbI = (NI + 255) / 256;
  scan_blocks<<<nbU, 256, 0, stream>>>(cnt_u, ofs_u, partials, NU);
  scan_partials<<<1, 1024, 0, stream>>>(partials, nbU);
  add_offsets<<<nbU, 256, 0, stream>>>(ofs_u, partials, NU, NE);
  scan_blocks<<<nbI, 256, 0, stream>>>(cnt_i, ofs_i, partials, NI);
  scan_partials<<<1, 1024, 0, stream>>>(partials, nbI);
  add_offsets<<<nbI, 256, 0, stream>>>(ofs_i, partials, NI, NE);

  copy_int<<<nbU, 256, 0, stream>>>(ofs_u, cur_u, NU);
  copy_int<<<nbI, 256, 0, stream>>>(ofs_i, cur_i, NI);
  place_kernel<<<(NE + 255) / 256, 256, 0, stream>>>(edge_src, edge_dst, cnt_u, cnt_i,
                                                     cur_u, cur_i, by_src, by_dst);

  conv_kernel<<<(NU * 16 + 255) / 256, 256, 0, stream>>>(user_feat, hbU0, NU * 16);
  conv_kernel<<<(NI * 16 + 255) / 256, 256, 0, stream>>>(item_feat, hbI0, NI * 16);

  gather_f32_kernel<<<(3 * NB * 64 + 255) / 256, 256, 0, stream>>>(
      user_feat, item_feat, users, pos_items, neg_items, out);

  const unsigned short* hu = hbU0;
  const unsigned short* hi = hbI0;
  for (int l = 0; l < 3; ++l) {
    unsigned short* hu_new = bufU[l & 1];
    unsigned short* hi_new = bufI[l & 1];
    gatherg_kernel<<<(NI + 3) / 4, 256, 0, stream>>>(ofs_i, by_dst, hu, g_i, c_i, NI);
    gatherg_kernel<<<(NU + 3) / 4, 256, 0, stream>>>(ofs_u, by_src, hi, g_u, c_u, NU);
    node_mfma_kernel<<<1024, 256, 0, stream>>>(g_i, c_i, hi, W1 + l * 4096, b1 + l * 64,
                                               W2 + l * 4096, b2 + l * 64, hi_new, NI / 16);
    node_mfma_kernel<<<1024, 256, 0, stream>>>(g_u, c_u, hu, W1 + l * 4096, b1 + l * 64,
                                               W2 + l * 4096, b2 + l * 64, hu_new, NU / 16);
    gather_bf_kernel<<<(3 * NB * 64 + 255) / 256, 256, 0, stream>>>(
        hu_new, hi_new, users, pos_items, neg_items, out, l + 1);
    hu = hu_new;
    hi = hi_new;
  }
}